// Round 9
// baseline (137.077 us; speedup 1.0000x reference)
//
#include <hip/hip_runtime.h>
#include <math.h>

#define PP 3072
#define NB 15
#define NM 8
#define XG 24      // x-groups of 128 per object
#define NCH 3      // y-chunks (1024 y each)
#define YW 128     // y per wave (8 waves * 128 = 1024 = chunk)

typedef _Float16 hv2 __attribute__((ext_vector_type(2)));

static __device__ __forceinline__ unsigned h2u(hv2 h) {
  return __builtin_bit_cast(unsigned, h);
}
static __device__ __forceinline__ hv2 u2h(unsigned u) {
  return __builtin_bit_cast(hv2, u);
}
static __device__ __forceinline__ hv2 hmin2(hv2 a, hv2 b) {
  return __builtin_elementwise_min(a, b);
}
static __device__ __forceinline__ unsigned pkf16(float lo, float hi) {
  hv2 h;
  h.x = (_Float16)lo;
  h.y = (_Float16)hi;
  return h2u(h);
}

// ws layout (bytes):
//  ytile:  [0, 737280)          uint4[15*3072]  {pk(gt,pred).x,.y,.z, byte}
//  part:   [737280, 5160960)    u32 [NCH][NB][XG][NM*128] packed f16 min-pairs
//  sums:   [5160960, 5161440)   float[15*8]  sum over x of sqrt(d0)+sqrt(d1)
//  cntf:   [5161440, 5161920)   float[15*8]  part sizes (as float)
#define WS_YTILE 0
#define WS_PART 737280
#define WS_SUMS 5160960
#define WS_CNTF 5161440

__global__ __launch_bounds__(256) void pack_kernel(
    const float* __restrict__ pred, const float* __restrict__ gt,
    const void* __restrict__ mask, uint4* __restrict__ yt,
    float* __restrict__ sums, float* __restrict__ cntf) {
  int i = blockIdx.x * 256 + threadIdx.x;
  if (blockIdx.x == 0 && threadIdx.x < 2 * NB * NM) {
    if (threadIdx.x < NB * NM) sums[threadIdx.x] = 0.f;
    else cntf[threadIdx.x - NB * NM] = 0.f;
  }
  if (i >= NB * PP) return;
  int b = i / PP, p = i - b * PP;

  // mask element-width probe (bool bytes vs int32 0/1)
  const uint4* pw = (const uint4*)mask;
  uint4 w0 = pw[0], w1 = pw[1], w2 = pw[2], w3 = pw[3];
  unsigned acc = (w0.x | w0.y | w0.z | w0.w | w1.x | w1.y | w1.z | w1.w |
                  w2.x | w2.y | w2.z | w2.w | w3.x | w3.y | w3.z | w3.w) &
                 0xFFFFFF00u;
  const bool bytemode = (acc != 0);
  const unsigned char* mb = (const unsigned char*)mask;
  const int* mi = (const int*)mask;

  unsigned byte = 0;
#pragma unroll
  for (int m = 0; m < NM; m++) {
    long q = (long)(b * NM + m) * PP + p;
    unsigned bit = bytemode ? (mb[q] != 0) : (mi[q] != 0);
    byte |= bit << m;
  }
  long g = (long)b * PP + p;
  uint4 t;
  t.x = pkf16(gt[g * 3 + 0], pred[g * 3 + 0]);  // lo = gt, hi = pred
  t.y = pkf16(gt[g * 3 + 1], pred[g * 3 + 1]);
  t.z = pkf16(gt[g * 3 + 2], pred[g * 3 + 2]);
  t.w = byte;
  yt[g] = t;
}

__global__ __launch_bounds__(512) void chamfer_main(
    const uint4* __restrict__ yt, unsigned* __restrict__ part) {
  const int xg = blockIdx.x, b = blockIdx.y, ch = blockIdx.z;
  const int tid = threadIdx.x;
  const int lane = tid & 63;
  const int w = tid >> 6;

  // this lane's two x points; swap halves so lo=pred_x, hi=gt_x
  const uint4 tx0 = yt[b * PP + xg * 128 + lane];
  const uint4 tx1 = yt[b * PP + xg * 128 + 64 + lane];
#define ROT(v) (((v) << 16) | ((v) >> 16))
  const hv2 x0x = u2h(ROT(tx0.x)), x0y = u2h(ROT(tx0.y)), x0z = u2h(ROT(tx0.z));
  const hv2 x1x = u2h(ROT(tx1.x)), x1y = u2h(ROT(tx1.y)), x1z = u2h(ROT(tx1.z));
#undef ROT

  hv2 acc0[NM], acc1[NM];
#pragma unroll
  for (int m = 0; m < NM; m++) {
    acc0[m] = u2h(0x7C007C00u);  // (+inf, +inf)
    acc1[m] = u2h(0x7C007C00u);
  }

  const uint4* __restrict__ ys = yt + b * PP + ch * 1024 + w * YW;
#pragma unroll 4
  for (int j = 0; j < YW; j++) {
    const uint4 t = ys[j];
    const unsigned byte = __builtin_amdgcn_readfirstlane(t.w);
    const hv2 qx = u2h(t.x), qy = u2h(t.y), qz = u2h(t.z);
    // packed distances: lo = |pred_x - gt_y|^2, hi = |gt_x - pred_y|^2
    hv2 s = x0x - qx;
    hv2 d0 = s * s;
    s = x0y - qy;
    d0 += s * s;
    s = x0z - qz;
    d0 += s * s;
    s = x1x - qx;
    hv2 d1 = s * s;
    s = x1y - qy;
    d1 += s * s;
    s = x1z - qz;
    d1 += s * s;
#pragma unroll
    for (int m = 0; m < NM; m++) {
      // wave-uniform selected addend: +0 keeps d, +inf disables
      const hv2 ad = u2h(((byte >> m) & 1) ? 0u : 0x7C007C00u);
      acc0[m] = hmin2(acc0[m], d0 + ad);
      acc1[m] = hmin2(acc1[m], d1 + ad);
    }
  }

  // cross-wave merge: per-wave slabs, then 8-way packed min
  __shared__ unsigned minw[8][NM][128];  // 32 KB
#pragma unroll
  for (int m = 0; m < NM; m++) {
    minw[w][m][lane] = h2u(acc0[m]);
    minw[w][m][lane + 64] = h2u(acc1[m]);
  }
  __syncthreads();

  unsigned* dst = part + (((long)ch * NB + b) * XG + xg) * (NM * 128);
  for (int it = tid; it < NM * 128; it += 512) {
    const int m = it >> 7, xl = it & 127;
    hv2 v = u2h(minw[0][m][xl]);
#pragma unroll
    for (int ww = 1; ww < 8; ww++) v = hmin2(v, u2h(minw[ww][m][xl]));
    dst[it] = h2u(v);
  }
}

__global__ __launch_bounds__(128) void obj_partial(
    const uint4* __restrict__ yt, const unsigned* __restrict__ part,
    float* __restrict__ sums, float* __restrict__ cntf) {
  const int b = blockIdx.x, xg = blockIdx.y;
  const int tid = threadIdx.x;
  const int lane = tid & 63, wv = tid >> 6;
  const unsigned byte = yt[(long)b * PP + xg * 128 + tid].w;
  const long base = ((long)b * XG + xg) * (NM * 128) + tid;
  const long cstride = (long)NB * XG * (NM * 128);

  __shared__ float red[2][NM][2];
#pragma unroll
  for (int m = 0; m < NM; m++) {
    hv2 v = u2h(part[base + m * 128]);
    v = hmin2(v, u2h(part[base + m * 128 + cstride]));
    v = hmin2(v, u2h(part[base + m * 128 + 2 * cstride]));
    const int bit = (byte >> m) & 1;
    float val = bit ? (sqrtf((float)v.x) + sqrtf((float)v.y)) : 0.f;
    float c = (float)bit;
    for (int off = 32; off > 0; off >>= 1) {
      val += __shfl_down(val, off);
      c += __shfl_down(c, off);
    }
    if (lane == 0) { red[wv][m][0] = val; red[wv][m][1] = c; }
  }
  __syncthreads();
  if (tid < NM) {
    atomicAdd(&sums[b * NM + tid], red[0][tid][0] + red[1][tid][0]);
    atomicAdd(&cntf[b * NM + tid], red[0][tid][1] + red[1][tid][1]);
  }
}

__global__ void scalar_kernel(const float* __restrict__ sums,
                              const float* __restrict__ cntf,
                              float* __restrict__ out) {
  const int lane = threadIdx.x;
  float o = 0.f;
  int c = 0;
  if (lane < NB) {
    float objsum = 0.f;
    int nvalid = 0;
#pragma unroll
    for (int m = 0; m < NM; m++) {
      int n = (int)(cntf[lane * NM + m] + 0.5f);
      if (n >= 2) {
        nvalid++;
        objsum += 0.5f * sums[lane * NM + m] / (float)n;
      }
    }
    if (nvalid > 0) { o = objsum / (float)nvalid; c = 1; }
  }
  for (int off = 32; off > 0; off >>= 1) {
    o += __shfl_down(o, off);
    c += __shfl_down(c, off);
  }
  if (lane == 0) out[0] = c > 0 ? o / (float)c : 0.f;
}

extern "C" void kernel_launch(void* const* d_in, const int* in_sizes, int n_in,
                              void* d_out, int out_size, void* d_ws, size_t ws_size,
                              hipStream_t stream) {
  const float* pred = (const float*)d_in[0];
  const float* gt = (const float*)d_in[1];
  const void* mask = d_in[3];

  char* ws = (char*)d_ws;
  uint4* yt = (uint4*)(ws + WS_YTILE);
  unsigned* part = (unsigned*)(ws + WS_PART);
  float* sums = (float*)(ws + WS_SUMS);
  float* cntf = (float*)(ws + WS_CNTF);
  float* out = (float*)d_out;

  pack_kernel<<<(NB * PP + 255) / 256, 256, 0, stream>>>(pred, gt, mask, yt,
                                                         sums, cntf);
  chamfer_main<<<dim3(XG, NB, NCH), 512, 0, stream>>>(yt, part);
  obj_partial<<<dim3(NB, XG), 128, 0, stream>>>(yt, part, sums, cntf);
  scalar_kernel<<<1, 64, 0, stream>>>(sums, cntf, out);
}